// Round 7
// baseline (281.796 us; speedup 1.0000x reference)
//
#include <hip/hip_runtime.h>
#include <stdint.h>

// WASLL R11: dispatch-count reduction (7 -> 4), kernels pinned at best-measured.
// R10 post-mortem closes the p2 ledger: 65us (R8 512tx16deep, 2 dom), 70us
// (R9 1024tx8deep, Occ 66%), 70us (R10 4 dom, +31MB window re-read). Occupancy
// 33->66% and domains 2->4 do NOT move p2 -> not residency-bound; R8 shape is
// the floor (max ILP depth, min traffic). Kernel sum ~185us vs total 273us ->
// ~85us is launch/gap overhead across 7 dispatches. R11:
//   - init_kernel removed: cursors zero-based (kernels add b<<13 / jb<<14),
//     reset by ONE hipMemsetAsync over the 8KB cursor region
//   - out[0] zeroed by p1 block 0 (stream-ordered before p3's atomics)
//   - p2 pair merged into one launch (grid 2 x n_pinb, per-block dim derive +
//     early exit); p3 pair likewise. Both-dims-active correctness: per-dim
//     ent2 halves when ws_size allows; else proven sequential 6-dispatch path.
//   - p2 = R8 verbatim (65us), p1/p3 = R9 1024-thread shape.

#define PINB_SHIFT 13
#define PINB_SIZE  (1 << PINB_SHIFT)      // 8192 pins/bucket = 32KB window
#define MAX_PINB   1024
#define JB_SHIFT   14
#define JB_SIZE    (1 << JB_SHIFT)        // 16384 slots/j-bucket (4096 nets)
#define MAX_JB     512
#define P1_CHUNK   8192                   // entries per P1 block
#define NTHR       1024                   // p1/p3 block size
#define NTHR2      512                    // p2 block size

__device__ __forceinline__ float wa4(float a, float b, float c, float d, float ig) {
    float ea = __expf(a * ig), eb = __expf(b * ig);
    float ec = __expf(c * ig), ed = __expf(d * ig);
    float na = __expf(-a * ig), nb = __expf(-b * ig);
    float nc = __expf(-c * ig), nd = __expf(-d * ig);
    float s_ep  = ea + eb + ec + ed;
    float s_xep = a * ea + b * eb + c * ec + d * ed;
    float s_en  = na + nb + nc + nd;
    float s_xen = a * na + b * nb + c * nc + d * nd;
    return s_xep / s_ep - s_xen / s_en;
}

// ---------------- P1: partition (pin, j) by 8192-pin bucket ----------------
// R9 shape: 1024 threads, 8 pins/thread; zero-based cur1; zeroes out[0].
__global__ __launch_bounds__(NTHR) void p1_partition(
    const int4* __restrict__ fnp4, int NP, int n_pinb,
    uint2* __restrict__ ent1, unsigned* __restrict__ cur1,
    float* __restrict__ out)
{
    __shared__ uint2    staged[P1_CHUNK];        // 64KB
    __shared__ unsigned hist[MAX_PINB];          // 4KB
    __shared__ unsigned scn[MAX_PINB];           // 4KB
    __shared__ unsigned gbase[MAX_PINB];         // 4KB
    const int base  = blockIdx.x * P1_CHUNK;
    const int valid = min(P1_CHUNK, NP - base);  // multiple of 4 (NP%4==0)
    const int t = threadIdx.x;

    if (blockIdx.x == 0 && t == 0) out[0] = 0.0f;   // before any p3 atomic

    for (int b = t; b < MAX_PINB; b += NTHR) hist[b] = 0;
    __syncthreads();

    // 8 pins/thread via int4; rank pass builds histogram
    unsigned pin[8], rnk[8];
    #pragma unroll
    for (int m4 = 0; m4 < 2; ++m4) {
        int k4 = t + NTHR * m4;
        int kk = 4 * k4;
        int4 v = make_int4(0, 0, 0, 0);
        if (kk < valid) v = fnp4[(base >> 2) + k4];
        pin[4*m4+0] = (unsigned)v.x; pin[4*m4+1] = (unsigned)v.y;
        pin[4*m4+2] = (unsigned)v.z; pin[4*m4+3] = (unsigned)v.w;
    }
    #pragma unroll
    for (int m4 = 0; m4 < 2; ++m4)
        #pragma unroll
        for (int c = 0; c < 4; ++c) {
            int kk = 4 * (t + NTHR * m4) + c;
            rnk[4*m4+c] = 0;
            if (kk < valid)
                rnk[4*m4+c] = atomicAdd(&hist[pin[4*m4+c] >> PINB_SHIFT], 1u);
        }
    __syncthreads();

    // wave-0 shuffle scan over MAX_PINB buckets (16 per lane); scn only
    if (t < 64) {
        unsigned v[16], s = 0;
        #pragma unroll
        for (int i = 0; i < 16; ++i) { v[i] = hist[t * 16 + i]; s += v[i]; }
        unsigned e = s;
        #pragma unroll
        for (int off = 1; off < 64; off <<= 1) {
            unsigned u = __shfl_up(e, off, 64);
            if (t >= off) e += u;
        }
        e -= s;  // exclusive base for this lane's chunk
        #pragma unroll
        for (int i = 0; i < 16; ++i) { scn[t * 16 + i] = e; e += v[i]; }
    }
    __syncthreads();

    // all-thread cursor atomics (zero-based; add bucket base here)
    for (int b = t; b < n_pinb; b += NTHR)
        if (hist[b])
            gbase[b] = ((unsigned)b << PINB_SHIFT) + atomicAdd(&cur1[b], hist[b]);
    __syncthreads();

    #pragma unroll
    for (int m4 = 0; m4 < 2; ++m4)
        #pragma unroll
        for (int c = 0; c < 4; ++c) {
            int kk = 4 * (t + NTHR * m4) + c;
            if (kk < valid) {
                unsigned p = pin[4*m4+c];
                staged[scn[p >> PINB_SHIFT] + rnk[4*m4+c]] =
                    make_uint2(p, (unsigned)(base + kk));
            }
        }
    __syncthreads();

    for (int k = t; k < valid; k += NTHR) {      // coalesced bucket-run writes
        uint2 e = staged[k];
        unsigned b = e.x >> PINB_SHIFT;
        ent1[gbase[b] + ((unsigned)k - scn[b])] = e;
    }
}

// ------- P2: LDS-window gather + repartition by 16384-slot j-bucket -------
// R8 structure verbatim (512t, 16-deep, win/staged aliasing), plus per-block
// dim derivation: blocks [0, nb) -> d=0, [nb, 2nb) -> d=1 (nb==0 forces d=1).
__global__ __launch_bounds__(NTHR2) void p2_gather(
    const uint2* __restrict__ ent1, const float2* __restrict__ pos2,
    const int* __restrict__ slrx_p, const int* __restrict__ slry_p,
    int nb_per_dim, int NP, int n_jb,
    uint2* __restrict__ ent2, unsigned ent2_stride,
    unsigned* __restrict__ cur2)
{
    int bb = blockIdx.x, d = 0;
    if (bb >= nb_per_dim) { d = 1; bb -= nb_per_dim; }
    const int slr = (d == 0) ? slrx_p[0] : slry_p[0];
    if (slr <= 1) return;                        // dim off: these blocks idle

    uint2*    ent2d = ent2 + (size_t)d * ent2_stride;
    unsigned* cur2d = cur2 + d * n_jb;

    // union: bytes [0,32K) = win (dead after gather), [0,64K) = staged
    __shared__ __align__(16) char smem[PINB_SIZE * sizeof(uint2) + 3 * MAX_JB * 4];
    float*    win    = (float*)smem;                                  // 32KB
    uint2*    staged = (uint2*)smem;                                  // 64KB
    unsigned* hist   = (unsigned*)(smem + PINB_SIZE * sizeof(uint2)); // 2KB
    unsigned* scn    = hist + MAX_JB;                                 // 2KB
    unsigned* gbase  = scn + MAX_JB;                                  // 2KB

    const int pbase = bb << PINB_SHIFT;
    const int valid = min(PINB_SIZE, NP - pbase);
    const int t = threadIdx.x;

    // 1) issue all entry loads up front (16/thread, latency exposed once)
    uint2 e[16];
    #pragma unroll
    for (int m = 0; m < 16; ++m) {
        int k = t + NTHR2 * m;
        e[m] = make_uint2(0u, 0u);
        if (k < valid) e[m] = ent1[pbase + k];
    }
    // 2) coalesced window load (overlaps entry loads) + hist zero
    for (int i = t; i < valid; i += NTHR2) {
        float2 p = pos2[pbase + i];
        win[i] = d ? p.y : p.x;
    }
    if (t < MAX_JB) hist[t] = 0;                 // NTHR2 == MAX_JB
    __syncthreads();

    // 3) LDS gather + rank/histogram
    float yv[16]; unsigned rnk[16];
    #pragma unroll
    for (int m = 0; m < 16; ++m) {
        int k = t + NTHR2 * m;
        yv[m] = (k < valid) ? win[e[m].x & (PINB_SIZE - 1)] : 0.0f;
    }
    #pragma unroll
    for (int m = 0; m < 16; ++m) {
        int k = t + NTHR2 * m;
        rnk[m] = 0;
        if (k < valid) rnk[m] = atomicAdd(&hist[e[m].y >> JB_SHIFT], 1u);
    }
    __syncthreads();                             // all win reads + hist atomics done

    // 4) wave-0 scan (8 buckets/lane); scn only, hist preserved
    if (t < 64) {
        unsigned v[8], s = 0;
        #pragma unroll
        for (int i = 0; i < 8; ++i) { v[i] = hist[t * 8 + i]; s += v[i]; }
        unsigned ex = s;
        #pragma unroll
        for (int off = 1; off < 64; off <<= 1) {
            unsigned u = __shfl_up(ex, off, 64);
            if (t >= off) ex += u;
        }
        ex -= s;
        #pragma unroll
        for (int i = 0; i < 8; ++i) { scn[t * 8 + i] = ex; ex += v[i]; }
    }
    __syncthreads();

    // 5) all-thread cursor atomics (zero-based; add j-bucket base here)
    for (int q = t; q < n_jb; q += NTHR2)
        if (hist[q])
            gbase[q] = ((unsigned)q << JB_SHIFT) + atomicAdd(&cur2d[q], hist[q]);
    __syncthreads();

    // 6) stage into the union (overwrites win -- all reads completed above)
    #pragma unroll
    for (int m = 0; m < 16; ++m) {
        int k = t + NTHR2 * m;
        if (k < valid)
            staged[scn[e[m].y >> JB_SHIFT] + rnk[m]] =
                make_uint2(e[m].y, __float_as_uint(yv[m]));
    }
    __syncthreads();

    // 7) coalesced bucket-run writes (~17-entry = 134B runs)
    for (int k = t; k < valid; k += NTHR2) {
        uint2 s2 = staged[k];
        unsigned jb = s2.x >> JB_SHIFT;
        ent2d[gbase[jb] + ((unsigned)k - scn[jb])] = s2;
    }
}

// ------------- P3: LDS slot tile, per-net wa4, global reduce -------------
// R9 shape (1024t) plus per-block dim derivation, mirroring p2.
__global__ __launch_bounds__(NTHR) void p3_compute(
    const uint2* __restrict__ ent2, unsigned ent2_stride,
    const float* __restrict__ wts, const float* __restrict__ ig_p,
    const int* __restrict__ slrx_p, const int* __restrict__ slry_p,
    int njb_per_dim, int NP, float* __restrict__ out)
{
    int jb = blockIdx.x, d = 0;
    if (jb >= njb_per_dim) { d = 1; jb -= njb_per_dim; }
    const int slr = (d == 0) ? slrx_p[0] : slry_p[0];
    if (slr <= 1) return;

    const uint2* ent2d = ent2 + (size_t)d * ent2_stride;

    __shared__ float ytmp[JB_SIZE];              // 64KB
    const int base_j = jb << JB_SHIFT;
    const int nslots = min(JB_SIZE, NP - base_j);  // multiple of 4
    const int t = threadIdx.x;
    const float ig = ig_p[0];

    for (int k = t; k < nslots; k += NTHR) {     // coalesced read, LDS scatter
        uint2 e = ent2d[base_j + k];
        ytmp[e.x & (JB_SIZE - 1)] = __uint_as_float(e.y);
    }
    __syncthreads();

    float val = 0.0f;
    const int nnets = nslots >> 2, bnet = base_j >> 2;
    const float4* y4 = (const float4*)ytmp;
    for (int i = t; i < nnets; i += NTHR) {
        float4 p = y4[i];                        // ds_read_b128
        val += wts[bnet + i] * wa4(p.x, p.y, p.z, p.w, ig);
    }

    #pragma unroll
    for (int off = 32; off > 0; off >>= 1) val += __shfl_down(val, off, 64);
    __syncthreads();
    if ((t & 63) == 0) ytmp[t >> 6] = val;
    __syncthreads();
    if (t == 0) {
        float s = 0.0f;
        #pragma unroll
        for (int w = 0; w < NTHR / 64; ++w) s += ytmp[w];
        atomicAdd(out, s);
    }
}

// ---------------- fallback: proven R1 gather kernel ----------------
__global__ __launch_bounds__(256) void wasll_fallback(
    const float2* __restrict__ pos, const int4* __restrict__ fnp4,
    const float* __restrict__ net_weights, const float* __restrict__ inv_gamma_p,
    const int* __restrict__ slrx_p, const int* __restrict__ slry_p,
    float* __restrict__ out, int num_nets)
{
    const float ig = inv_gamma_p[0];
    const float dx = (slrx_p[0] > 1) ? 1.0f : 0.0f;
    const float dy = (slry_p[0] > 1) ? 1.0f : 0.0f;
    int net = blockIdx.x * blockDim.x + threadIdx.x;
    float val = 0.0f;
    if (net < num_nets) {
        int4 idx = fnp4[net];
        float2 p0 = pos[idx.x], p1 = pos[idx.y], p2 = pos[idx.z], p3 = pos[idx.w];
        val = net_weights[net] * (dx * wa4(p0.x, p1.x, p2.x, p3.x, ig)
                                + dy * wa4(p0.y, p1.y, p2.y, p3.y, ig));
    }
    #pragma unroll
    for (int off = 32; off > 0; off >>= 1) val += __shfl_down(val, off, 64);
    __shared__ float smem[4];
    if ((threadIdx.x & 63) == 0) smem[threadIdx.x >> 6] = val;
    __syncthreads();
    if (threadIdx.x == 0)
        atomicAdd(out, smem[0] + smem[1] + smem[2] + smem[3]);
}

__global__ void zero_out_kernel(float* __restrict__ out) { out[0] = 0.0f; }

extern "C" void kernel_launch(void* const* d_in, const int* in_sizes, int n_in,
                              void* d_out, int out_size, void* d_ws, size_t ws_size,
                              hipStream_t stream) {
    const float* posf        = (const float*)d_in[0];
    const int*   fnp         = (const int*)d_in[1];
    const float* net_weights = (const float*)d_in[4];
    const float* inv_gamma   = (const float*)d_in[7];
    const int*   slrx        = (const int*)d_in[8];
    const int*   slry        = (const int*)d_in[9];
    float*       out         = (float*)d_out;
    const int    N  = in_sizes[4];
    const int    NP = in_sizes[1];

    const int n_pinb = (NP + PINB_SIZE - 1) >> PINB_SHIFT;
    const int n_jb   = (NP + JB_SIZE - 1) >> JB_SHIFT;

    size_t off = 0;
    auto carve = [&](size_t bytes) { size_t o = off; off += (bytes + 255) & ~size_t(255); return o; };
    size_t o_ent1 = carve((size_t)n_pinb * PINB_SIZE * sizeof(uint2));
    size_t o_cur1 = carve((size_t)n_pinb * sizeof(unsigned));
    size_t o_cur2 = carve((size_t)2 * n_jb * sizeof(unsigned));
    size_t ent2_bytes = (size_t)n_jb * JB_SIZE * sizeof(uint2);
    size_t o_ent2 = carve(ent2_bytes);
    const size_t cur_span = (o_cur2 + (size_t)2 * n_jb * sizeof(unsigned)) - o_cur1;

    const bool ok = (NP == 4 * N) && (NP % 4 == 0) &&
                    (n_pinb <= MAX_PINB) && (n_jb <= MAX_JB) && (off <= ws_size);
    if (!ok) {
        hipLaunchKernelGGL(zero_out_kernel, dim3(1), dim3(1), 0, stream, out);
        const int block = 256, grid = (N + block - 1) / block;
        hipLaunchKernelGGL(wasll_fallback, dim3(grid), dim3(block), 0, stream,
                           (const float2*)posf, (const int4*)fnp, net_weights,
                           inv_gamma, slrx, slry, out, N);
        return;
    }

    // dual-ent2 mode: per-dim halves allow merging the two p2 (and p3) launches
    const bool dual = (off + ent2_bytes) <= ws_size;
    const unsigned ent2_stride = dual ? (unsigned)((size_t)n_jb * JB_SIZE) : 0u;

    char* ws = (char*)d_ws;
    uint2*    ent1 = (uint2*)(ws + o_ent1);
    uint2*    ent2 = (uint2*)(ws + o_ent2);
    unsigned* cur1 = (unsigned*)(ws + o_cur1);
    unsigned* cur2 = (unsigned*)(ws + o_cur2);

    // one async reset of both cursor arrays (they are adjacent in the carve)
    hipMemsetAsync(ws + o_cur1, 0, cur_span, stream);

    const int g1 = (NP + P1_CHUNK - 1) / P1_CHUNK;
    hipLaunchKernelGGL(p1_partition, dim3(g1), dim3(NTHR), 0, stream,
                       (const int4*)fnp, NP, n_pinb, ent1, cur1, out);

    if (dual) {
        // merged: one p2 launch covers both dims, likewise p3 (4 dispatches total)
        hipLaunchKernelGGL(p2_gather, dim3(2 * n_pinb), dim3(NTHR2), 0, stream,
                           ent1, (const float2*)posf, slrx, slry,
                           n_pinb, NP, n_jb, ent2, ent2_stride, cur2);
        hipLaunchKernelGGL(p3_compute, dim3(2 * n_jb), dim3(NTHR), 0, stream,
                           ent2, ent2_stride, net_weights, inv_gamma,
                           slrx, slry, n_jb, NP, out);
    } else {
        // sequential proven path: shared ent2, d=0 then d=1 (nb_per_dim=0 forces d=1)
        hipLaunchKernelGGL(p2_gather, dim3(n_pinb), dim3(NTHR2), 0, stream,
                           ent1, (const float2*)posf, slrx, slry,
                           n_pinb, NP, n_jb, ent2, 0u, cur2);
        hipLaunchKernelGGL(p3_compute, dim3(n_jb), dim3(NTHR), 0, stream,
                           ent2, 0u, net_weights, inv_gamma,
                           slrx, slry, n_jb, NP, out);
        hipLaunchKernelGGL(p2_gather, dim3(n_pinb), dim3(NTHR2), 0, stream,
                           ent1, (const float2*)posf, slrx, slry,
                           0, NP, n_jb, ent2, 0u, cur2);
        hipLaunchKernelGGL(p3_compute, dim3(n_jb), dim3(NTHR), 0, stream,
                           ent2, 0u, net_weights, inv_gamma,
                           slrx, slry, 0, NP, out);
    }
}

// Round 8
// 269.661 us; speedup vs baseline: 1.0450x; 1.0450x over previous
//
#include <hip/hip_runtime.h>
#include <stdint.h>

// WASLL R12: keep R11's overhead wins, restore R8's p2 configuration.
// R11 accounting: non-p2 time 203->189us (dispatch merge + init removal WORK)
// but p2 regressed 65->93us (same FETCH/WRITE/VGPR, hbm 2.1->1.5TB/s, VALU
// 10.3->7.6% -- pure latency exposure). p2's R11 deltas: mixed noop/real grid,
// direct p1->p2 adjacency (lost the 2-noop-launch writeback-drain spacing),
// carve reorder. R12 cherry-picks:
//   KEEP: memset cursor init (zero-based, -1 dispatch), merged p3 (-1
//         dispatch), dual per-dim ent2, p1/p3 1024t shape.
//   RESTORE: p2 = R8 exact config -- separate launch per dim, d as kernel
//         arg, noop p2(d=0) between p1 and real p2 (R8 spacing), original
//         carve order (ent1, ent2, cursors; dual half at tail).
// 5 dispatches (memset+4) in dual mode, 6-kernel sequential fallback.

#define PINB_SHIFT 13
#define PINB_SIZE  (1 << PINB_SHIFT)      // 8192 pins/bucket = 32KB window
#define MAX_PINB   1024
#define JB_SHIFT   14
#define JB_SIZE    (1 << JB_SHIFT)        // 16384 slots/j-bucket (4096 nets)
#define MAX_JB     512
#define P1_CHUNK   8192                   // entries per P1 block
#define NTHR       1024                   // p1/p3 block size
#define NTHR2      512                    // p2 block size

__device__ __forceinline__ float wa4(float a, float b, float c, float d, float ig) {
    float ea = __expf(a * ig), eb = __expf(b * ig);
    float ec = __expf(c * ig), ed = __expf(d * ig);
    float na = __expf(-a * ig), nb = __expf(-b * ig);
    float nc = __expf(-c * ig), nd = __expf(-d * ig);
    float s_ep  = ea + eb + ec + ed;
    float s_xep = a * ea + b * eb + c * ec + d * ed;
    float s_en  = na + nb + nc + nd;
    float s_xen = a * na + b * nb + c * nc + d * nd;
    return s_xep / s_ep - s_xen / s_en;
}

// ---------------- P1: partition (pin, j) by 8192-pin bucket ----------------
// 1024 threads, 8 pins/thread; zero-based cur1; zeroes out[0].
__global__ __launch_bounds__(NTHR) void p1_partition(
    const int4* __restrict__ fnp4, int NP, int n_pinb,
    uint2* __restrict__ ent1, unsigned* __restrict__ cur1,
    float* __restrict__ out)
{
    __shared__ uint2    staged[P1_CHUNK];        // 64KB
    __shared__ unsigned hist[MAX_PINB];          // 4KB
    __shared__ unsigned scn[MAX_PINB];           // 4KB
    __shared__ unsigned gbase[MAX_PINB];         // 4KB
    const int base  = blockIdx.x * P1_CHUNK;
    const int valid = min(P1_CHUNK, NP - base);  // multiple of 4 (NP%4==0)
    const int t = threadIdx.x;

    if (blockIdx.x == 0 && t == 0) out[0] = 0.0f;   // before any p3 atomic

    for (int b = t; b < MAX_PINB; b += NTHR) hist[b] = 0;
    __syncthreads();

    // 8 pins/thread via int4; rank pass builds histogram
    unsigned pin[8], rnk[8];
    #pragma unroll
    for (int m4 = 0; m4 < 2; ++m4) {
        int k4 = t + NTHR * m4;
        int kk = 4 * k4;
        int4 v = make_int4(0, 0, 0, 0);
        if (kk < valid) v = fnp4[(base >> 2) + k4];
        pin[4*m4+0] = (unsigned)v.x; pin[4*m4+1] = (unsigned)v.y;
        pin[4*m4+2] = (unsigned)v.z; pin[4*m4+3] = (unsigned)v.w;
    }
    #pragma unroll
    for (int m4 = 0; m4 < 2; ++m4)
        #pragma unroll
        for (int c = 0; c < 4; ++c) {
            int kk = 4 * (t + NTHR * m4) + c;
            rnk[4*m4+c] = 0;
            if (kk < valid)
                rnk[4*m4+c] = atomicAdd(&hist[pin[4*m4+c] >> PINB_SHIFT], 1u);
        }
    __syncthreads();

    // wave-0 shuffle scan over MAX_PINB buckets (16 per lane); scn only
    if (t < 64) {
        unsigned v[16], s = 0;
        #pragma unroll
        for (int i = 0; i < 16; ++i) { v[i] = hist[t * 16 + i]; s += v[i]; }
        unsigned e = s;
        #pragma unroll
        for (int off = 1; off < 64; off <<= 1) {
            unsigned u = __shfl_up(e, off, 64);
            if (t >= off) e += u;
        }
        e -= s;  // exclusive base for this lane's chunk
        #pragma unroll
        for (int i = 0; i < 16; ++i) { scn[t * 16 + i] = e; e += v[i]; }
    }
    __syncthreads();

    // all-thread cursor atomics (zero-based; add bucket base in-register)
    for (int b = t; b < n_pinb; b += NTHR)
        if (hist[b])
            gbase[b] = ((unsigned)b << PINB_SHIFT) + atomicAdd(&cur1[b], hist[b]);
    __syncthreads();

    #pragma unroll
    for (int m4 = 0; m4 < 2; ++m4)
        #pragma unroll
        for (int c = 0; c < 4; ++c) {
            int kk = 4 * (t + NTHR * m4) + c;
            if (kk < valid) {
                unsigned p = pin[4*m4+c];
                staged[scn[p >> PINB_SHIFT] + rnk[4*m4+c]] =
                    make_uint2(p, (unsigned)(base + kk));
            }
        }
    __syncthreads();

    for (int k = t; k < valid; k += NTHR) {      // coalesced bucket-run writes
        uint2 e = staged[k];
        unsigned b = e.x >> PINB_SHIFT;
        ent1[gbase[b] + ((unsigned)k - scn[b])] = e;
    }
}

// ------- P2: LDS-window gather + repartition by 16384-slot j-bucket -------
// R8 configuration: d is a kernel argument, one launch per dim; 512t x
// 16-deep, single round, win/staged aliasing.
__global__ __launch_bounds__(NTHR2) void p2_gather(
    const uint2* __restrict__ ent1, const float2* __restrict__ pos2,
    const int* __restrict__ slrx_p, const int* __restrict__ slry_p,
    int d, int NP, int n_jb,
    uint2* __restrict__ ent2, unsigned* __restrict__ cur2)
{
    const int slr = (d == 0) ? slrx_p[0] : slry_p[0];
    if (slr <= 1) return;                        // dim off: whole launch no-op

    // union: bytes [0,32K) = win (dead after gather), [0,64K) = staged
    __shared__ __align__(16) char smem[PINB_SIZE * sizeof(uint2) + 3 * MAX_JB * 4];
    float*    win    = (float*)smem;                                  // 32KB
    uint2*    staged = (uint2*)smem;                                  // 64KB
    unsigned* hist   = (unsigned*)(smem + PINB_SIZE * sizeof(uint2)); // 2KB
    unsigned* scn    = hist + MAX_JB;                                 // 2KB
    unsigned* gbase  = scn + MAX_JB;                                  // 2KB

    const int pbase = blockIdx.x << PINB_SHIFT;
    const int valid = min(PINB_SIZE, NP - pbase);
    const int t = threadIdx.x;

    // 1) issue all entry loads up front (16/thread, latency exposed once)
    uint2 e[16];
    #pragma unroll
    for (int m = 0; m < 16; ++m) {
        int k = t + NTHR2 * m;
        e[m] = make_uint2(0u, 0u);
        if (k < valid) e[m] = ent1[pbase + k];
    }
    // 2) coalesced window load (overlaps entry loads) + hist zero
    for (int i = t; i < valid; i += NTHR2) {
        float2 p = pos2[pbase + i];
        win[i] = d ? p.y : p.x;
    }
    if (t < MAX_JB) hist[t] = 0;                 // NTHR2 == MAX_JB
    __syncthreads();

    // 3) LDS gather + rank/histogram
    float yv[16]; unsigned rnk[16];
    #pragma unroll
    for (int m = 0; m < 16; ++m) {
        int k = t + NTHR2 * m;
        yv[m] = (k < valid) ? win[e[m].x & (PINB_SIZE - 1)] : 0.0f;
    }
    #pragma unroll
    for (int m = 0; m < 16; ++m) {
        int k = t + NTHR2 * m;
        rnk[m] = 0;
        if (k < valid) rnk[m] = atomicAdd(&hist[e[m].y >> JB_SHIFT], 1u);
    }
    __syncthreads();                             // all win reads + hist atomics done

    // 4) wave-0 scan (8 buckets/lane); scn only, hist preserved
    if (t < 64) {
        unsigned v[8], s = 0;
        #pragma unroll
        for (int i = 0; i < 8; ++i) { v[i] = hist[t * 8 + i]; s += v[i]; }
        unsigned ex = s;
        #pragma unroll
        for (int off = 1; off < 64; off <<= 1) {
            unsigned u = __shfl_up(ex, off, 64);
            if (t >= off) ex += u;
        }
        ex -= s;
        #pragma unroll
        for (int i = 0; i < 8; ++i) { scn[t * 8 + i] = ex; ex += v[i]; }
    }
    __syncthreads();

    // 5) all-thread cursor atomics (zero-based; add j-bucket base in-register)
    for (int q = t; q < n_jb; q += NTHR2)
        if (hist[q])
            gbase[q] = ((unsigned)q << JB_SHIFT) + atomicAdd(&cur2[q], hist[q]);
    __syncthreads();

    // 6) stage into the union (overwrites win -- all reads completed above)
    #pragma unroll
    for (int m = 0; m < 16; ++m) {
        int k = t + NTHR2 * m;
        if (k < valid)
            staged[scn[e[m].y >> JB_SHIFT] + rnk[m]] =
                make_uint2(e[m].y, __float_as_uint(yv[m]));
    }
    __syncthreads();

    // 7) coalesced bucket-run writes (~17-entry = 134B runs)
    for (int k = t; k < valid; k += NTHR2) {
        uint2 s2 = staged[k];
        unsigned jb = s2.x >> JB_SHIFT;
        ent2[gbase[jb] + ((unsigned)k - scn[jb])] = s2;
    }
}

// ------------- P3: LDS slot tile, per-net wa4, global reduce -------------
// Merged grid (2 x n_jb) with per-block dim derivation; 1024 threads.
__global__ __launch_bounds__(NTHR) void p3_compute(
    const uint2* __restrict__ ent2, unsigned ent2_stride,
    const float* __restrict__ wts, const float* __restrict__ ig_p,
    const int* __restrict__ slrx_p, const int* __restrict__ slry_p,
    int njb_per_dim, int NP, float* __restrict__ out)
{
    int jb = blockIdx.x, d = 0;
    if (jb >= njb_per_dim) { d = 1; jb -= njb_per_dim; }
    const int slr = (d == 0) ? slrx_p[0] : slry_p[0];
    if (slr <= 1) return;

    const uint2* ent2d = ent2 + (size_t)d * ent2_stride;

    __shared__ float ytmp[JB_SIZE];              // 64KB
    const int base_j = jb << JB_SHIFT;
    const int nslots = min(JB_SIZE, NP - base_j);  // multiple of 4
    const int t = threadIdx.x;
    const float ig = ig_p[0];

    for (int k = t; k < nslots; k += NTHR) {     // coalesced read, LDS scatter
        uint2 e = ent2d[base_j + k];
        ytmp[e.x & (JB_SIZE - 1)] = __uint_as_float(e.y);
    }
    __syncthreads();

    float val = 0.0f;
    const int nnets = nslots >> 2, bnet = base_j >> 2;
    const float4* y4 = (const float4*)ytmp;
    for (int i = t; i < nnets; i += NTHR) {
        float4 p = y4[i];                        // ds_read_b128
        val += wts[bnet + i] * wa4(p.x, p.y, p.z, p.w, ig);
    }

    #pragma unroll
    for (int off = 32; off > 0; off >>= 1) val += __shfl_down(val, off, 64);
    __syncthreads();
    if ((t & 63) == 0) ytmp[t >> 6] = val;
    __syncthreads();
    if (t == 0) {
        float s = 0.0f;
        #pragma unroll
        for (int w = 0; w < NTHR / 64; ++w) s += ytmp[w];
        atomicAdd(out, s);
    }
}

// ---------------- fallback: proven R1 gather kernel ----------------
__global__ __launch_bounds__(256) void wasll_fallback(
    const float2* __restrict__ pos, const int4* __restrict__ fnp4,
    const float* __restrict__ net_weights, const float* __restrict__ inv_gamma_p,
    const int* __restrict__ slrx_p, const int* __restrict__ slry_p,
    float* __restrict__ out, int num_nets)
{
    const float ig = inv_gamma_p[0];
    const float dx = (slrx_p[0] > 1) ? 1.0f : 0.0f;
    const float dy = (slry_p[0] > 1) ? 1.0f : 0.0f;
    int net = blockIdx.x * blockDim.x + threadIdx.x;
    float val = 0.0f;
    if (net < num_nets) {
        int4 idx = fnp4[net];
        float2 p0 = pos[idx.x], p1 = pos[idx.y], p2 = pos[idx.z], p3 = pos[idx.w];
        val = net_weights[net] * (dx * wa4(p0.x, p1.x, p2.x, p3.x, ig)
                                + dy * wa4(p0.y, p1.y, p2.y, p3.y, ig));
    }
    #pragma unroll
    for (int off = 32; off > 0; off >>= 1) val += __shfl_down(val, off, 64);
    __shared__ float smem[4];
    if ((threadIdx.x & 63) == 0) smem[threadIdx.x >> 6] = val;
    __syncthreads();
    if (threadIdx.x == 0)
        atomicAdd(out, smem[0] + smem[1] + smem[2] + smem[3]);
}

__global__ void zero_out_kernel(float* __restrict__ out) { out[0] = 0.0f; }

extern "C" void kernel_launch(void* const* d_in, const int* in_sizes, int n_in,
                              void* d_out, int out_size, void* d_ws, size_t ws_size,
                              hipStream_t stream) {
    const float* posf        = (const float*)d_in[0];
    const int*   fnp         = (const int*)d_in[1];
    const float* net_weights = (const float*)d_in[4];
    const float* inv_gamma   = (const float*)d_in[7];
    const int*   slrx        = (const int*)d_in[8];
    const int*   slry        = (const int*)d_in[9];
    float*       out         = (float*)d_out;
    const int    N  = in_sizes[4];
    const int    NP = in_sizes[1];

    const int n_pinb = (NP + PINB_SIZE - 1) >> PINB_SHIFT;
    const int n_jb   = (NP + JB_SIZE - 1) >> JB_SHIFT;

    // carve: R4-lineage order (ent1, ent2, cur1, cur2), dual ent2 half at tail
    size_t off = 0;
    auto carve = [&](size_t bytes) { size_t o = off; off += (bytes + 255) & ~size_t(255); return o; };
    size_t ent2_bytes = (size_t)n_jb * JB_SIZE * sizeof(uint2);
    size_t o_ent1 = carve((size_t)n_pinb * PINB_SIZE * sizeof(uint2));
    size_t o_ent2 = carve(ent2_bytes);
    size_t o_cur1 = carve((size_t)n_pinb * sizeof(unsigned));
    size_t o_cur2 = carve((size_t)2 * n_jb * sizeof(unsigned));
    const size_t cur_span = (o_cur2 + (size_t)2 * n_jb * sizeof(unsigned)) - o_cur1;
    size_t o_ent2b = carve(ent2_bytes);          // dual half (may exceed ws)

    const bool ok = (NP == 4 * N) && (NP % 4 == 0) &&
                    (n_pinb <= MAX_PINB) && (n_jb <= MAX_JB) &&
                    (o_ent2b <= ws_size);        // core buffers must fit
    if (!ok) {
        hipLaunchKernelGGL(zero_out_kernel, dim3(1), dim3(1), 0, stream, out);
        const int block = 256, grid = (N + block - 1) / block;
        hipLaunchKernelGGL(wasll_fallback, dim3(grid), dim3(block), 0, stream,
                           (const float2*)posf, (const int4*)fnp, net_weights,
                           inv_gamma, slrx, slry, out, N);
        return;
    }

    const bool dual = (off <= ws_size);          // second ent2 half fits
    // element stride between per-dim ent2 regions (256-aligned => /8 exact)
    const unsigned ent2_stride = dual ? (unsigned)((o_ent2b - o_ent2) / sizeof(uint2)) : 0u;

    char* ws = (char*)d_ws;
    uint2*    ent1 = (uint2*)(ws + o_ent1);
    uint2*    ent2 = (uint2*)(ws + o_ent2);
    uint2*    ent2b = dual ? (uint2*)(ws + o_ent2b) : ent2;
    unsigned* cur1 = (unsigned*)(ws + o_cur1);
    unsigned* cur2 = (unsigned*)(ws + o_cur2);

    // one async reset of both cursor arrays (adjacent in the carve)
    hipMemsetAsync(ws + o_cur1, 0, cur_span, stream);

    const int g1 = (NP + P1_CHUNK - 1) / P1_CHUNK;
    hipLaunchKernelGGL(p1_partition, dim3(g1), dim3(NTHR), 0, stream,
                       (const int4*)fnp, NP, n_pinb, ent1, cur1, out);

    if (dual) {
        // p2 per dim (R8 spacing: noop d=0 launch precedes real d=1 work),
        // then ONE merged p3 over both dims. 5 dispatches total.
        hipLaunchKernelGGL(p2_gather, dim3(n_pinb), dim3(NTHR2), 0, stream,
                           ent1, (const float2*)posf, slrx, slry, 0,
                           NP, n_jb, ent2, cur2);
        hipLaunchKernelGGL(p2_gather, dim3(n_pinb), dim3(NTHR2), 0, stream,
                           ent1, (const float2*)posf, slrx, slry, 1,
                           NP, n_jb, ent2b, cur2 + n_jb);
        hipLaunchKernelGGL(p3_compute, dim3(2 * n_jb), dim3(NTHR), 0, stream,
                           ent2, ent2_stride, net_weights, inv_gamma,
                           slrx, slry, n_jb, NP, out);
    } else {
        // sequential proven path: shared ent2, d=0 then d=1
        hipLaunchKernelGGL(p2_gather, dim3(n_pinb), dim3(NTHR2), 0, stream,
                           ent1, (const float2*)posf, slrx, slry, 0,
                           NP, n_jb, ent2, cur2);
        hipLaunchKernelGGL(p3_compute, dim3(n_jb), dim3(NTHR), 0, stream,
                           ent2, 0u, net_weights, inv_gamma,
                           slrx, slry, n_jb, NP, out);   // all blocks d=0
        hipLaunchKernelGGL(p2_gather, dim3(n_pinb), dim3(NTHR2), 0, stream,
                           ent1, (const float2*)posf, slrx, slry, 1,
                           NP, n_jb, ent2, cur2 + n_jb);
        hipLaunchKernelGGL(p3_compute, dim3(n_jb), dim3(NTHR), 0, stream,
                           ent2, 0u, net_weights, inv_gamma,
                           slrx, slry, 0, NP, out);      // all blocks d=1
    }
}